// Round 9
// baseline (42385.287 us; speedup 1.0000x reference)
//
#include <hip/hip_runtime.h>

#define TSTEPS 1920
#define NB 128
#define HIDN 256
#define LATN 128
#define EPSF 1e-5f

typedef __attribute__((ext_vector_type(8))) short bf16x8;
typedef __attribute__((ext_vector_type(4))) float f32x4;

__device__ __forceinline__ unsigned short f2bf(float x) {
    unsigned u = __builtin_bit_cast(unsigned, x);
    unsigned r = (u + 0x7fffu + ((u >> 16) & 1u)) >> 16;
    return (unsigned short)r;
}
__device__ __forceinline__ float bf2f(unsigned short h) {
    unsigned u = ((unsigned)h) << 16;
    return __builtin_bit_cast(float, u);
}
__device__ __forceinline__ float fsig(float x) {
    float e = __expf(-fabsf(x));
    float s = 1.f / (1.f + e);
    return x >= 0.f ? s : 1.f - s;
}
__device__ __forceinline__ float ftanh(float x) {
    float e = __expf(-2.f * fabsf(x));
    float r = (1.f - e) / (1.f + e);
    return x >= 0.f ? r : -r;
}
__device__ __forceinline__ float fleaky(float x) { return x > 0.f ? x : 0.2f * x; }
__device__ __forceinline__ bf16x8 bcast16(uint4 v) { return __builtin_bit_cast(bf16x8, v); }

__device__ __forceinline__ unsigned aload(const unsigned* p) {
    return __hip_atomic_load(p, __ATOMIC_RELAXED, __HIP_MEMORY_SCOPE_AGENT);
}
__device__ __forceinline__ unsigned long long aload64(const unsigned long long* p) {
    return __hip_atomic_load(p, __ATOMIC_RELAXED, __HIP_MEMORY_SCOPE_AGENT);
}
__device__ __forceinline__ void astore(unsigned* p, unsigned v) {
    __hip_atomic_store(p, v, __ATOMIC_RELAXED, __HIP_MEMORY_SCOPE_AGENT);
}

#define MFMA(a, b, c) __builtin_amdgcn_mfma_f32_16x16x32_bf16((a), (b), (c), 0, 0, 0)

#define FLG(g, s) ((g) * 8 + (s)) * 32
#define HPLANE(g, layer, buf) ((((g) * 2 + (layer)) * 2 + (buf)) * 2048)

__global__ void init_sync(unsigned* hbuf, unsigned* flags) {
    int i = blockIdx.x * 256 + threadIdx.x;
    if (i < 131072) hbuf[i] = 0u;
    if (i < 4096) flags[i] = 0u;
}

// ---- pack W [1024][KA+KB] -> sliced MFMA B-frag order, hi/lo bf16 ----
__global__ void pack_bfrag_sliced(const float* __restrict__ A, const float* __restrict__ Bsrc,
                                  int KA, int KB,
                                  unsigned short* __restrict__ hi, unsigned short* __restrict__ lo) {
    int e = blockIdx.x * 256 + threadIdx.x;
    int K = KA + KB;
    int KT = K >> 5;
    if (e >= 1024 * K) return;
    int j = e & 7;
    int l = (e >> 3) & 63;
    int r = e >> 9;
    int kt = r % KT;
    int r2 = r / KT;
    int v = r2 & 7;
    int w = r2 >> 3;
    int n = (v >> 1) * 256 + 32 * w + 16 * (v & 1) + (l & 15);
    int k = kt * 32 + (l >> 4) * 8 + j;
    float val = (k < KA) ? A[n * KA + k] : Bsrc[n * KB + (k - KA)];
    unsigned short h = f2bf(val);
    hi[e] = h;
    lo[e] = f2bf(val - bf2f(h));
}

// ---- pack sW1 [128][256] -> B-frag order per (wave, kt): bf16-hi ----
__global__ void pack_sw1frag(const float* __restrict__ sW1, unsigned short* __restrict__ out) {
    int e = blockIdx.x * 256 + threadIdx.x;
    if (e >= 32768) return;
    int j3 = e & 7;
    int l = (e >> 3) & 63;
    int r = e >> 9;           // w*8 + kt
    int kt = r & 7, w = r >> 3;
    int n = w * 16 + (l & 15);
    int k = kt * 32 + (l >> 4) * 8 + j3;
    out[e] = f2bf(sW1[n * 256 + k]);
}

__global__ void pack4T(const float* __restrict__ W, int N, int K, float* __restrict__ out) {
    int e = blockIdx.x * 256 + threadIdx.x;
    if (e >= N * K) return;
    int j = e & 3;
    int rest = e >> 2;
    int n = rest % N;
    int k4 = rest / N;
    out[e] = W[n * K + 4 * k4 + j];
}

__global__ void prep_b1(const float* __restrict__ bih1, const float* __restrict__ bhh1,
                        float* __restrict__ b1sum) {
    int i = blockIdx.x * 256 + threadIdx.x;
    if (i < 1024) b1sum[i] = bih1[i] + bhh1[i];
}

__global__ void np_head(const float* __restrict__ z, const int* __restrict__ labels,
                        const float* __restrict__ emb_W, const float* __restrict__ np_W,
                        const float* __restrict__ np_b, const float* __restrict__ np_g,
                        const float* __restrict__ np_be, float* __restrict__ x_const) {
    int b = blockIdx.x;
    int j = threadIdx.x;
    __shared__ float xc[LATN + HIDN];
    __shared__ float red[8];
    int lab = labels[b];
    if (j < LATN) xc[j] = z[b * LATN + j];
    float e = emb_W[lab * HIDN + j];
    xc[LATN + j] = e;
    __syncthreads();
    float d = np_b[j];
    for (int k = 0; k < LATN + HIDN; ++k) d += xc[k] * np_W[j * (LATN + HIDN) + k];
    int lane = j & 63, wv = j >> 6;
    float s = d, s2 = d * d;
    for (int o = 1; o < 64; o <<= 1) { s += __shfl_xor(s, o); s2 += __shfl_xor(s2, o); }
    if (lane == 0) { red[wv] = s; red[4 + wv] = s2; }
    __syncthreads();
    float S = red[0] + red[1] + red[2] + red[3];
    float S2 = red[4] + red[5] + red[6] + red[7];
    float m = S * (1.f / 256.f);
    float var = S2 * (1.f / 256.f) - m * m;
    float h = fleaky((d - m) * rsqrtf(var + EPSF) * np_g[j] + np_be[j]);
    x_const[b * 512 + j] = h;
    x_const[b * 512 + 256 + j] = e;
}

__global__ void __launch_bounds__(1024) xw0_kernel(const float* __restrict__ x_const,
                                                   const float4* __restrict__ Wih0T4,
                                                   const float* __restrict__ bih0,
                                                   const float* __restrict__ bhh0,
                                                   float* __restrict__ xw0) {
    int b = blockIdx.x;
    int g = threadIdx.x;
    __shared__ float xc[512];
    if (g < 512) xc[g] = x_const[b * 512 + g];
    __syncthreads();
    const float4* xc4 = (const float4*)xc;
    float4 acc = {0.f, 0.f, 0.f, 0.f};
#pragma unroll 8
    for (int k4 = 0; k4 < 128; ++k4) {
        float4 w = Wih0T4[k4 * 1024 + g];
        float4 x = xc4[k4];
        acc.x = fmaf(w.x, x.x, acc.x);
        acc.y = fmaf(w.y, x.y, acc.y);
        acc.z = fmaf(w.z, x.z, acc.z);
        acc.w = fmaf(w.w, x.w, acc.w);
    }
    xw0[b * 1024 + g] = bih0[g] + bhh0[g] + ((acc.x + acc.y) + (acc.z + acc.w));
}

// ==== main: 64 blocks (8 XCDs x 8 slices) x 512 thr; 2 independent 8-row groups/block,
// sub-phases interleaved so each group's sync latency hides under the other's compute ====
__global__ void __launch_bounds__(512, 2) lstm_coop(
    const uint4* __restrict__ whh0h, const uint4* __restrict__ whh0l,
    const uint4* __restrict__ w1h, const uint4* __restrict__ w1l,
    const unsigned short* __restrict__ sw1f_g, const float* __restrict__ xw0g,
    const float* __restrict__ b1sum, const float* __restrict__ sb1,
    const float* __restrict__ sg, const float* __restrict__ sbe,
    const float* __restrict__ sW2, const float* __restrict__ sb2,
    unsigned* __restrict__ hbuf, unsigned* __restrict__ flags,
    float* __restrict__ base_out, float* __restrict__ hsum_out) {
    extern __shared__ char smem[];
    char* pAhi = smem;                                        // [16][1024B]
    char* pAlo = smem + 16384;
    char* pBhi = smem + 32768;
    char* pBlo = smem + 49152;
    unsigned short* sw1f = (unsigned short*)(smem + 65536);   // 64KB
    float* gates0 = (float*)(smem + 131072);                  // [16][132] shared A/B
    float* gates1 = (float*)(smem + 139520);
    float* s1b    = (float*)(smem + 147968);                  // ends 156416

    const int g8 = blockIdx.x & 7;     // XCD / pair index
    const int W = blockIdx.x >> 3;     // slice 0..7
    const int tid = threadIdx.x;
    const int l = tid & 63;
    const int v = tid >> 6;            // wave 0..7
    const int ln16 = l & 15;
    const int kg = l >> 4;

    for (int i = tid; i < 16384; i += 512)
        ((unsigned*)sw1f)[i] = ((const unsigned*)sw1f_g)[i];
    for (int i = tid; i < 4096; i += 512) {
        ((unsigned*)pAhi)[i] = 0u; ((unsigned*)pAlo)[i] = 0u;
        ((unsigned*)pBhi)[i] = 0u; ((unsigned*)pBlo)[i] = 0u;
    }

    // resident weights (shared by both groups)
    uint4 b0h[8], b0l[8];
#pragma unroll
    for (int kt = 0; kt < 8; ++kt) {
        int idx = ((W * 8 + v) * 8 + kt) * 64 + l;
        b0h[kt] = whh0h[idx];
        b0l[kt] = whh0l[idx];
    }
    uint4 w1hR[16], w1lR[16];
#pragma unroll
    for (int kt = 0; kt < 16; ++kt) {
        int idx = ((W * 8 + v) * 16 + kt) * 64 + l;
        w1hR[kt] = w1h[idx];
        w1lR[kt] = w1l[idx];
    }

    const int r8 = (tid >> 5) & 7;     // UPD row 0..7 (guarded tid<256)
    const int ul = tid & 31;
    const int ug = 32 * W + ul;
    float xwiA[4], xwiB[4], b1v[4];
#pragma unroll
    for (int gt = 0; gt < 4; ++gt) {
        xwiA[gt] = xw0g[(16 * g8 + r8) * 1024 + gt * 256 + ug];
        xwiB[gt] = xw0g[(16 * g8 + 8 + r8) * 1024 + gt * 256 + ug];
        b1v[gt] = b1sum[gt * 256 + ug];
    }
    float c0A = 0.f, c1A = 0.f, hsA = 0.f;
    float c0B = 0.f, c1B = 0.f, hsB = 0.f;

    const float sb1a = sb1[2 * l], sb1b = sb1[2 * l + 1];
    const float sga = sg[2 * l], sgb = sg[2 * l + 1];
    const float sbea = sbe[2 * l], sbeb = sbe[2 * l + 1];
    const float sw2a = sW2[2 * l], sw2b = sW2[2 * l + 1];
    const float sb2v = sb2[0];

    unsigned* h0A[2] = {hbuf + HPLANE(2 * g8, 0, 0), hbuf + HPLANE(2 * g8, 0, 1)};
    unsigned* h1A[2] = {hbuf + HPLANE(2 * g8, 1, 0), hbuf + HPLANE(2 * g8, 1, 1)};
    unsigned* h0B[2] = {hbuf + HPLANE(2 * g8 + 1, 0, 0), hbuf + HPLANE(2 * g8 + 1, 0, 1)};
    unsigned* h1B[2] = {hbuf + HPLANE(2 * g8 + 1, 1, 0), hbuf + HPLANE(2 * g8 + 1, 1, 1)};
    unsigned* flA = flags + FLG(2 * g8, W);
    unsigned* flAb = flags + FLG(2 * g8, 0);
    unsigned* flB = flags + FLG(2 * g8 + 1, W);
    unsigned* flBb = flags + FLG(2 * g8 + 1, 0);

    const int abase = ln16 * 1024;
    const int aswz = (ln16 & 7) << 4;
    const int kgo = kg * 16;
    const int gcol = (v >> 1) * 32 + (v & 1) * 16 + ln16;

#define WAITF(BASE, tgtv)                                                        \
    {                                                                            \
        unsigned tgt = (unsigned)(tgtv);                                         \
        while (true) {                                                           \
            unsigned val = (l < 8) ? aload((BASE) + l * 32) : tgt;               \
            if (__all((int)(val >= tgt))) break;                                 \
            __builtin_amdgcn_s_sleep(1);                                         \
        }                                                                        \
    }                                                                            \
    asm volatile("" ::: "memory");

#define STAGE2(DH, DL, SRC0, SRC1)                                               \
    {                                                                            \
        const unsigned long long* sA_ = (const unsigned long long*)(SRC0);       \
        const unsigned long long* sB_ = (const unsigned long long*)(SRC1);       \
        _Pragma("unroll")                                                        \
        for (int it = 0; it < 4; ++it) {                                         \
            int i2 = tid + 512 * it;                                             \
            int rr = i2 >> 7, u2 = i2 & 127;                                     \
            int prow = rr & 7;                                                   \
            int bas = (rr >> 3) * 512;                                           \
            const unsigned long long* sp = (rr < 8) ? sA_ : sB_;                 \
            unsigned long long vv = aload64(sp + prow * 128 + u2);               \
            unsigned w0_ = (unsigned)vv, w1_ = (unsigned)(vv >> 32);             \
            int off = prow * 1024 + ((bas + 4 * u2) ^ (prow << 4));              \
            *(unsigned*)((DH) + off) = (w0_ >> 16) | (w1_ & 0xffff0000u);        \
            *(unsigned*)((DL) + off) = (w0_ & 0xffffu) | (w1_ << 16);            \
        }                                                                        \
    }

#define MVPHASE(PH, PL)                                                          \
    {                                                                            \
        f32x4 a0 = {0.f, 0.f, 0.f, 0.f};                                         \
        f32x4 a1 = {0.f, 0.f, 0.f, 0.f};                                         \
        f32x4 ahd = {0.f, 0.f, 0.f, 0.f};                                        \
        _Pragma("unroll")                                                        \
        for (int kt = 0; kt < 8; ++kt) {                                         \
            int aoff = abase + ((kt * 64 + kgo) ^ aswz);                         \
            bf16x8 ahi = bcast16(*(const uint4*)((PH) + aoff));                  \
            bf16x8 alo = bcast16(*(const uint4*)((PL) + aoff));                  \
            bf16x8 bh = bcast16(b0h[kt]);                                        \
            bf16x8 bl = bcast16(b0l[kt]);                                        \
            a0 = MFMA(ahi, bh, a0); a0 = MFMA(alo, bh, a0); a0 = MFMA(ahi, bl, a0); \
            bf16x8 ch = bcast16(w1hR[kt]);                                       \
            bf16x8 cl = bcast16(w1lR[kt]);                                       \
            a1 = MFMA(ahi, ch, a1); a1 = MFMA(alo, ch, a1); a1 = MFMA(ahi, cl, a1); \
        }                                                                        \
        _Pragma("unroll")                                                        \
        for (int kt = 8; kt < 16; ++kt) {                                        \
            int aoff = abase + ((kt * 64 + kgo) ^ aswz);                         \
            bf16x8 ahi = bcast16(*(const uint4*)((PH) + aoff));                  \
            bf16x8 alo = bcast16(*(const uint4*)((PL) + aoff));                  \
            bf16x8 ch = bcast16(w1hR[kt]);                                       \
            bf16x8 cl = bcast16(w1lR[kt]);                                       \
            a1 = MFMA(ahi, ch, a1); a1 = MFMA(alo, ch, a1); a1 = MFMA(ahi, cl, a1); \
            bf16x8 bsw = bcast16(*(const uint4*)&sw1f[((v * 8 + (kt - 8)) * 64 + l) * 8]); \
            ahd = MFMA(ahi, bsw, ahd); ahd = MFMA(alo, bsw, ahd);                \
        }                                                                        \
        _Pragma("unroll")                                                        \
        for (int r = 0; r < 4; ++r) {                                            \
            gates0[(kg * 4 + r) * 132 + gcol] = a0[r];                           \
            gates1[(kg * 4 + r) * 132 + gcol] = a1[r];                           \
            s1b[(kg * 4 + r) * 132 + v * 16 + ln16] = ahd[r];                    \
        }                                                                        \
    }

#define HEADMV(PH, PL)                                                           \
    {                                                                            \
        f32x4 ahd = {0.f, 0.f, 0.f, 0.f};                                        \
        _Pragma("unroll")                                                        \
        for (int kt = 8; kt < 16; ++kt) {                                        \
            int aoff = abase + ((kt * 64 + kgo) ^ aswz);                         \
            bf16x8 ahi = bcast16(*(const uint4*)((PH) + aoff));                  \
            bf16x8 alo = bcast16(*(const uint4*)((PL) + aoff));                  \
            bf16x8 bsw = bcast16(*(const uint4*)&sw1f[((v * 8 + (kt - 8)) * 64 + l) * 8]); \
            ahd = MFMA(ahi, bsw, ahd); ahd = MFMA(alo, bsw, ahd);                \
        }                                                                        \
        _Pragma("unroll")                                                        \
        for (int r = 0; r < 4; ++r) s1b[(kg * 4 + r) * 132 + v * 16 + ln16] = ahd[r]; \
    }

#define UPDPUB(pp, H0B, H1B, XWI, C0, C1, HS)                                    \
    if (tid < 256) {                                                             \
        float i_ = gates0[r8 * 132 + ul] + (XWI)[0];                             \
        float f_ = gates0[r8 * 132 + 32 + ul] + (XWI)[1];                        \
        float g_ = gates0[r8 * 132 + 64 + ul] + (XWI)[2];                        \
        float o_ = gates0[r8 * 132 + 96 + ul] + (XWI)[3];                        \
        C0 = fsig(f_) * C0 + fsig(i_) * ftanh(g_);                               \
        float h = fsig(o_) * ftanh(C0);                                          \
        unsigned short hh = f2bf(h);                                             \
        unsigned short ll = f2bf(h - bf2f(hh));                                  \
        astore((H0B)[(pp) & 1] + r8 * 256 + ug, ((unsigned)hh << 16) | (unsigned)ll); \
        if ((pp) > 0) {                                                          \
            i_ = gates1[r8 * 132 + ul] + b1v[0];                                 \
            f_ = gates1[r8 * 132 + 32 + ul] + b1v[1];                            \
            g_ = gates1[r8 * 132 + 64 + ul] + b1v[2];                            \
            o_ = gates1[r8 * 132 + 96 + ul] + b1v[3];                            \
            C1 = fsig(f_) * C1 + fsig(i_) * ftanh(g_);                           \
            h = fsig(o_) * ftanh(C1);                                            \
            HS += h;                                                             \
            hh = f2bf(h);                                                        \
            ll = f2bf(h - bf2f(hh));                                             \
            astore((H1B)[((pp) - 1) & 1] + r8 * 256 + ug, ((unsigned)hh << 16) | (unsigned)ll); \
        }                                                                        \
    }

#define HEADFIN(GROW, tout)                                                      \
    if (v < 2) {                                                                 \
        _Pragma("unroll")                                                        \
        for (int r4 = 0; r4 < 4; ++r4) {                                         \
            int hrw = v * 4 + r4;                                                \
            float2 sv = *(const float2*)&s1b[hrw * 132 + 2 * l];                 \
            float sA = sv.x + sb1a, sB = sv.y + sb1b;                            \
            float ssum = sA + sB, ssq = sA * sA + sB * sB;                       \
            _Pragma("unroll")                                                    \
            for (int o = 1; o < 64; o <<= 1) {                                   \
                ssum += __shfl_xor(ssum, o); ssq += __shfl_xor(ssq, o);          \
            }                                                                    \
            float m = ssum * (1.f / 128.f);                                      \
            float var = ssq * (1.f / 128.f) - m * m;                             \
            float rstd = rsqrtf(var + EPSF);                                     \
            float p0 = fleaky((sA - m) * rstd * sga + sbea);                     \
            float p1 = fleaky((sB - m) * rstd * sgb + sbeb);                     \
            float qd = p0 * sw2a + p1 * sw2b;                                    \
            _Pragma("unroll")                                                    \
            for (int o = 1; o < 64; o <<= 1) qd += __shfl_xor(qd, o);            \
            if (l == 0) base_out[((GROW) + hrw) * TSTEPS + (tout)] = ftanh(qd + sb2v); \
        }                                                                        \
    }

#define SUBPHASE(pp, PH, PL, H0B, H1B, FLW, FLWB, XWI, C0, C1, HS, GROW)         \
    WAITF(FLWB, pp);                                                             \
    STAGE2(PH, PL, (H0B)[((pp) - 1) & 1], (H1B)[(pp) & 1]);                      \
    __syncthreads();                                                             \
    MVPHASE(PH, PL);                                                             \
    __syncthreads();                                                             \
    UPDPUB(pp, H0B, H1B, XWI, C0, C1, HS);                                       \
    asm volatile("s_waitcnt vmcnt(0)" ::: "memory");                             \
    __syncthreads();                                                             \
    if (tid == 0) astore(FLW, (unsigned)((pp) + 1));                             \
    if ((pp) >= 2) HEADFIN(GROW, (pp) - 2);

    __syncthreads();

    for (int p = 0; p <= TSTEPS; ++p) {
        SUBPHASE(p, pAhi, pAlo, h0A, h1A, flA, flAb, xwiA, c0A, c1A, hsA, 16 * g8);
        SUBPHASE(p, pBhi, pBlo, h0B, h1B, flB, flBb, xwiB, c0B, c1B, hsB, 16 * g8 + 8);
    }

    // ---- epilogue: base(1919) for both groups ----
    WAITF(flAb, TSTEPS + 1);
    STAGE2(pAhi, pAlo, h0A[(TSTEPS - 1) & 1], h1A[(TSTEPS - 1) & 1]);
    __syncthreads();
    HEADMV(pAhi, pAlo);
    __syncthreads();
    HEADFIN(16 * g8, TSTEPS - 1);
    __syncthreads();
    WAITF(flBb, TSTEPS + 1);
    STAGE2(pBhi, pBlo, h0B[(TSTEPS - 1) & 1], h1B[(TSTEPS - 1) & 1]);
    __syncthreads();
    HEADMV(pBhi, pBlo);
    __syncthreads();
    HEADFIN(16 * g8 + 8, TSTEPS - 1);
    if (tid < 256) {
        hsum_out[(16 * g8 + r8) * HIDN + ug] = hsA;
        hsum_out[(16 * g8 + 8 + r8) * HIDN + ug] = hsB;
    }
#undef WAITF
#undef STAGE2
#undef MVPHASE
#undef HEADMV
#undef UPDPUB
#undef HEADFIN
#undef SUBPHASE
}

__global__ void out_kernel(const float* __restrict__ hsum, const float* __restrict__ oW1,
                           const float* __restrict__ ob1, const float* __restrict__ og,
                           const float* __restrict__ obe, const float* __restrict__ oW2,
                           const float* __restrict__ ob2, const float* __restrict__ base,
                           const int* __restrict__ labels, const float* __restrict__ stress_w,
                           const float* __restrict__ amu_w, const float* __restrict__ amu_b,
                           float* __restrict__ out) {
    int b = blockIdx.x;
    int tid = threadIdx.x;
    int lane = tid & 63, wv = tid >> 6;
    __shared__ float havg[256];
    __shared__ float red[8];
    __shared__ float params[3];
    __shared__ float e_row[TSTEPS];
    havg[tid] = hsum[b * 256 + tid] * (1.f / (float)TSTEPS);
    __syncthreads();
    float d1 = 0.f;
    if (tid < 128) {
        d1 = ob1[tid];
        for (int k = 0; k < 256; ++k) d1 += havg[k] * oW1[tid * 256 + k];
    }
    float s = d1, s2 = d1 * d1;
    for (int o = 1; o < 64; o <<= 1) { s += __shfl_xor(s, o); s2 += __shfl_xor(s2, o); }
    if (lane == 0 && wv < 2) { red[wv] = s; red[2 + wv] = s2; }
    __syncthreads();
    float m = (red[0] + red[1]) * (1.f / 128.f);
    float var = (red[2] + red[3]) * (1.f / 128.f) - m * m;
    float rstd = rsqrtf(var + EPSF);
    float p = 0.f;
    if (tid < 128) p = fleaky((d1 - m) * rstd * og[tid] + obe[tid]);
    float q0 = tid < 128 ? p * oW2[0 * 128 + tid] : 0.f;
    float q1 = tid < 128 ? p * oW2[1 * 128 + tid] : 0.f;
    float q2 = tid < 128 ? p * oW2[2 * 128 + tid] : 0.f;
    for (int o = 1; o < 64; o <<= 1) {
        q0 += __shfl_xor(q0, o); q1 += __shfl_xor(q1, o); q2 += __shfl_xor(q2, o);
    }
    __syncthreads();
    if (lane == 0 && wv < 2) { red[wv] = q0; red[2 + wv] = q1; red[4 + wv] = q2; }
    __syncthreads();
    if (tid == 0) {
        float op0 = red[0] + red[1] + ob2[0];
        float op1 = red[2] + red[3] + ob2[1];
        float op2 = red[4] + red[5] + ob2[2];
        params[0] = 0.23f + 0.04f * ftanh(op0);
        params[1] = 2.0f + 1.5f * ftanh(op1);
        params[2] = 3.14159265358979f * fsig(op2);
    }
    __syncthreads();
    float freq = params[0], amp = params[1], ph = params[2];
    for (int t = tid; t < TSTEPS; t += 256) {
        float x = freq * ((float)TSTEPS * (float)t / (float)(TSTEPS - 1));
        x -= floorf(x);
        float osc = amp * __sinf(6.28318530717958647f * x + ph);
        e_row[t] = 0.6f * base[b * TSTEPS + t] + 0.4f * osc;
    }
    __syncthreads();
    int lab = labels[b];
    float sw = stress_w[0];
    float w0 = amu_w[0], w1 = amu_w[1], w2 = amu_w[2], ab = amu_b[0];
    for (int t = tid; t < TSTEPS; t += 256) {
        float e = e_row[t];
        float r;
        if (lab == 1) r = e;
        else if (lab == 2) r = sw * e;
        else if (lab == 3) {
            float em = t > 0 ? e_row[t - 1] : 0.f;
            float ep = t < TSTEPS - 1 ? e_row[t + 1] : 0.f;
            r = w0 * em + w1 * e + w2 * ep + ab;
        } else r = 0.f;
        out[b * TSTEPS + t] = r;
    }
}

extern "C" void kernel_launch(void* const* d_in, const int* in_sizes, int n_in,
                              void* d_out, int out_size, void* d_ws, size_t ws_size,
                              hipStream_t stream) {
    (void)in_sizes; (void)n_in; (void)out_size; (void)ws_size;
    const float* z      = (const float*)d_in[0];
    const int* labels   = (const int*)d_in[1];
    const float* emb_W  = (const float*)d_in[2];
    const float* np_W   = (const float*)d_in[3];
    const float* np_b   = (const float*)d_in[4];
    const float* np_g   = (const float*)d_in[5];
    const float* np_be  = (const float*)d_in[6];
    const float* Wih0   = (const float*)d_in[7];
    const float* Whh0   = (const float*)d_in[8];
    const float* bih0   = (const float*)d_in[9];
    const float* bhh0   = (const float*)d_in[10];
    const float* Wih1   = (const float*)d_in[11];
    const float* Whh1   = (const float*)d_in[12];
    const float* bih1   = (const float*)d_in[13];
    const float* bhh1   = (const float*)d_in[14];
    const float* oW1    = (const float*)d_in[15];
    const float* ob1    = (const float*)d_in[16];
    const float* og     = (const float*)d_in[17];
    const float* obe    = (const float*)d_in[18];
    const float* oW2    = (const float*)d_in[19];
    const float* ob2    = (const float*)d_in[20];
    const float* sW1    = (const float*)d_in[21];
    const float* sb1    = (const float*)d_in[22];
    const float* sg     = (const float*)d_in[23];
    const float* sbe    = (const float*)d_in[24];
    const float* sW2    = (const float*)d_in[25];
    const float* sb2    = (const float*)d_in[26];
    const float* stressw= (const float*)d_in[27];
    const float* amu_w  = (const float*)d_in[28];
    const float* amu_b  = (const float*)d_in[29];
    float* out = (float*)d_out;

    uint8_t* ws = (uint8_t*)d_ws;
    size_t off = 0;
    unsigned short* whh0h = (unsigned short*)(ws + off); off += (size_t)1024 * 256 * 2;
    unsigned short* whh0l = (unsigned short*)(ws + off); off += (size_t)1024 * 256 * 2;
    unsigned short* w1h   = (unsigned short*)(ws + off); off += (size_t)1024 * 512 * 2;
    unsigned short* w1l   = (unsigned short*)(ws + off); off += (size_t)1024 * 512 * 2;
    unsigned short* sw1fg = (unsigned short*)(ws + off); off += (size_t)32768 * 2;
    float* Wih0T4 = (float*)(ws + off); off += (size_t)1024 * 512 * 4;
    float* x_const= (float*)(ws + off); off += (size_t)NB * 512 * 4;
    float* xw0    = (float*)(ws + off); off += (size_t)NB * 1024 * 4;
    float* b1sum  = (float*)(ws + off); off += (size_t)1024 * 4;
    float* hsum   = (float*)(ws + off); off += (size_t)NB * 256 * 4;
    float* basef  = (float*)(ws + off); off += (size_t)NB * TSTEPS * 4;
    off = (off + 255) & ~(size_t)255;
    unsigned* hbuf = (unsigned*)(ws + off); off += (size_t)131072 * 4;
    unsigned* flags= (unsigned*)(ws + off); off += (size_t)4096 * 4;

    init_sync<<<512, 256, 0, stream>>>(hbuf, flags);
    pack_bfrag_sliced<<<1024, 256, 0, stream>>>(Whh0, nullptr, 256, 0, whh0h, whh0l);
    pack_bfrag_sliced<<<2048, 256, 0, stream>>>(Wih1, Whh1, 256, 256, w1h, w1l);
    pack_sw1frag<<<128, 256, 0, stream>>>(sW1, sw1fg);
    pack4T<<<2048, 256, 0, stream>>>(Wih0, 1024, 512, Wih0T4);
    prep_b1<<<4, 256, 0, stream>>>(bih1, bhh1, b1sum);

    np_head<<<NB, 256, 0, stream>>>(z, labels, emb_W, np_W, np_b, np_g, np_be, x_const);
    xw0_kernel<<<NB, 1024, 0, stream>>>(x_const, (const float4*)Wih0T4, bih0, bhh0, xw0);
    lstm_coop<<<64, 512, 156416, stream>>>((const uint4*)whh0h, (const uint4*)whh0l,
                                           (const uint4*)w1h, (const uint4*)w1l,
                                           sw1fg, xw0, b1sum, sb1, sg, sbe, sW2, sb2,
                                           hbuf, flags, basef, hsum);
    out_kernel<<<NB, 256, 0, stream>>>(hsum, oW1, ob1, og, obe, oW2, ob2, basef, labels,
                                       stressw, amu_w, amu_b, out);
}

// Round 11
// 26771.216 us; speedup vs baseline: 1.5832x; 1.5832x over previous
//
#include <hip/hip_runtime.h>

#define TSTEPS 1920
#define NB 128
#define HIDN 256
#define LATN 128
#define EPSF 1e-5f

typedef __attribute__((ext_vector_type(8))) short bf16x8;
typedef __attribute__((ext_vector_type(4))) float f32x4;

__device__ __forceinline__ unsigned short f2bf(float x) {
    unsigned u = __builtin_bit_cast(unsigned, x);
    unsigned r = (u + 0x7fffu + ((u >> 16) & 1u)) >> 16;
    return (unsigned short)r;
}
__device__ __forceinline__ float bf2f(unsigned short h) {
    unsigned u = ((unsigned)h) << 16;
    return __builtin_bit_cast(float, u);
}
__device__ __forceinline__ float u32lo(unsigned w) {
    return __builtin_bit_cast(float, w << 16);
}
__device__ __forceinline__ float u32hi(unsigned w) {
    return __builtin_bit_cast(float, w & 0xFFFF0000u);
}
__device__ __forceinline__ float fsig(float x) {
    float e = __expf(-fabsf(x));
    float s = 1.f / (1.f + e);
    return x >= 0.f ? s : 1.f - s;
}
__device__ __forceinline__ float ftanh(float x) {
    float e = __expf(-2.f * fabsf(x));
    float r = (1.f - e) / (1.f + e);
    return x >= 0.f ? r : -r;
}
__device__ __forceinline__ float fleaky(float x) { return x > 0.f ? x : 0.2f * x; }
__device__ __forceinline__ bf16x8 bcast16(uint4 v) { return __builtin_bit_cast(bf16x8, v); }

__device__ __forceinline__ unsigned aload(const unsigned* p) {
    return __hip_atomic_load(p, __ATOMIC_RELAXED, __HIP_MEMORY_SCOPE_AGENT);
}
__device__ __forceinline__ unsigned long long aload64(const unsigned long long* p) {
    return __hip_atomic_load(p, __ATOMIC_RELAXED, __HIP_MEMORY_SCOPE_AGENT);
}
__device__ __forceinline__ void astore(unsigned* p, unsigned v) {
    __hip_atomic_store(p, v, __ATOMIC_RELAXED, __HIP_MEMORY_SCOPE_AGENT);
}

#define MFMA(a, b, c) __builtin_amdgcn_mfma_f32_16x16x32_bf16((a), (b), (c), 0, 0, 0)

#define FLG(ph, g, s) (((ph) * 8 + (g)) * 8 + (s)) * 32
#define HPLANE(g, layer, buf) (((g) * 2 + (layer)) * 2 + (buf)) * 4096

__global__ void init_sync(unsigned* hbuf, unsigned* flags) {
    int i = blockIdx.x * 256 + threadIdx.x;
    if (i < 131072) hbuf[i] = 0u;
    if (i < 4096) flags[i] = 0u;
}

// ---- pack W [1024][KA+KB] -> sliced MFMA B-frag order, hi/lo bf16 ----
__global__ void pack_bfrag_sliced(const float* __restrict__ A, const float* __restrict__ Bsrc,
                                  int KA, int KB,
                                  unsigned short* __restrict__ hi, unsigned short* __restrict__ lo) {
    int e = blockIdx.x * 256 + threadIdx.x;
    int K = KA + KB;
    int KT = K >> 5;
    if (e >= 1024 * K) return;
    int j = e & 7;
    int l = (e >> 3) & 63;
    int r = e >> 9;
    int kt = r % KT;
    int r2 = r / KT;
    int v = r2 & 7;
    int w = r2 >> 3;
    int n = (v >> 1) * 256 + 32 * w + 16 * (v & 1) + (l & 15);
    int k = kt * 32 + (l >> 4) * 8 + j;
    float val = (k < KA) ? A[n * KA + k] : Bsrc[n * KB + (k - KA)];
    unsigned short h = f2bf(val);
    hi[e] = h;
    lo[e] = f2bf(val - bf2f(h));
}

// ---- pack sW1 [128][256] -> [k/8][j][8] bf16 ----
__global__ void pack_sw1k8(const float* __restrict__ sW1, unsigned short* __restrict__ out) {
    int e = blockIdx.x * 256 + threadIdx.x;
    if (e >= 256 * 128) return;
    int j = e & 127, k = e >> 7;
    out[((k >> 3) * 128 + j) * 8 + (k & 7)] = f2bf(sW1[j * 256 + k]);
}

__global__ void pack4T(const float* __restrict__ W, int N, int K, float* __restrict__ out) {
    int e = blockIdx.x * 256 + threadIdx.x;
    if (e >= N * K) return;
    int j = e & 3;
    int rest = e >> 2;
    int n = rest % N;
    int k4 = rest / N;
    out[e] = W[n * K + 4 * k4 + j];
}

__global__ void prep_b1(const float* __restrict__ bih1, const float* __restrict__ bhh1,
                        float* __restrict__ b1sum) {
    int i = blockIdx.x * 256 + threadIdx.x;
    if (i < 1024) b1sum[i] = bih1[i] + bhh1[i];
}

__global__ void np_head(const float* __restrict__ z, const int* __restrict__ labels,
                        const float* __restrict__ emb_W, const float* __restrict__ np_W,
                        const float* __restrict__ np_b, const float* __restrict__ np_g,
                        const float* __restrict__ np_be, float* __restrict__ x_const) {
    int b = blockIdx.x;
    int j = threadIdx.x;
    __shared__ float xc[LATN + HIDN];
    __shared__ float red[8];
    int lab = labels[b];
    if (j < LATN) xc[j] = z[b * LATN + j];
    float e = emb_W[lab * HIDN + j];
    xc[LATN + j] = e;
    __syncthreads();
    float d = np_b[j];
    for (int k = 0; k < LATN + HIDN; ++k) d += xc[k] * np_W[j * (LATN + HIDN) + k];
    int lane = j & 63, wv = j >> 6;
    float s = d, s2 = d * d;
    for (int o = 1; o < 64; o <<= 1) { s += __shfl_xor(s, o); s2 += __shfl_xor(s2, o); }
    if (lane == 0) { red[wv] = s; red[4 + wv] = s2; }
    __syncthreads();
    float S = red[0] + red[1] + red[2] + red[3];
    float S2 = red[4] + red[5] + red[6] + red[7];
    float m = S * (1.f / 256.f);
    float var = S2 * (1.f / 256.f) - m * m;
    float h = fleaky((d - m) * rsqrtf(var + EPSF) * np_g[j] + np_be[j]);
    x_const[b * 512 + j] = h;
    x_const[b * 512 + 256 + j] = e;
}

__global__ void __launch_bounds__(1024) xw0_kernel(const float* __restrict__ x_const,
                                                   const float4* __restrict__ Wih0T4,
                                                   const float* __restrict__ bih0,
                                                   const float* __restrict__ bhh0,
                                                   float* __restrict__ xw0) {
    int b = blockIdx.x;
    int g = threadIdx.x;
    __shared__ float xc[512];
    if (g < 512) xc[g] = x_const[b * 512 + g];
    __syncthreads();
    const float4* xc4 = (const float4*)xc;
    float4 acc = {0.f, 0.f, 0.f, 0.f};
#pragma unroll 8
    for (int k4 = 0; k4 < 128; ++k4) {
        float4 w = Wih0T4[k4 * 1024 + g];
        float4 x = xc4[k4];
        acc.x = fmaf(w.x, x.x, acc.x);
        acc.y = fmaf(w.y, x.y, acc.y);
        acc.z = fmaf(w.z, x.z, acc.z);
        acc.w = fmaf(w.w, x.w, acc.w);
    }
    xw0[b * 1024 + g] = bih0[g] + bhh0[g] + ((acc.x + acc.y) + (acc.z + acc.w));
}

// ==== main recurrent kernel: 64 blocks (8 groups x 8 slices) x 512 thr ====
__global__ void __launch_bounds__(512, 2) lstm_coop(
    const uint4* __restrict__ whh0h, const uint4* __restrict__ whh0l,
    const uint4* __restrict__ w1h, const uint4* __restrict__ w1l,
    const unsigned short* __restrict__ sw1k8_g, const float* __restrict__ xw0g,
    const float* __restrict__ b1sum, const float* __restrict__ sb1,
    const float* __restrict__ sg, const float* __restrict__ sbe,
    const float* __restrict__ sW2, const float* __restrict__ sb2,
    unsigned* __restrict__ hbuf, unsigned* __restrict__ flags,
    float* __restrict__ base_out, float* __restrict__ hsum_out) {
    extern __shared__ char smem[];
    unsigned short* hhi = (unsigned short*)smem;
    unsigned short* hlo = (unsigned short*)(smem + 16384);
    unsigned short* sw1s = (unsigned short*)(smem + 32768);
    float* gatesL = (float*)(smem + 98304);
    float* ppart = (float*)(smem + 106752);
    char* hhiB = smem;
    char* hloB = smem + 16384;

    const int gidx = blockIdx.x & 7;
    const int W = blockIdx.x >> 3;
    const int g16 = gidx * 16;
    const int tid = threadIdx.x;
    const int l = tid & 63;
    const int v = tid >> 6;
    const int ln16 = l & 15;
    const int kg = l >> 4;

    for (int i = tid; i < 256 * 128; i += 512) sw1s[i] = sw1k8_g[i];
    for (int i = tid; i < 8192; i += 512) { hhi[i] = 0; hlo[i] = 0; }

    uint4 b0h[8], b0l[8];
#pragma unroll
    for (int kt = 0; kt < 8; ++kt) {
        int idx = ((W * 8 + v) * 8 + kt) * 64 + l;
        b0h[kt] = whh0h[idx];
        b0l[kt] = whh0l[idx];
    }
    uint4 w1hR[16], w1lR[16];
#pragma unroll
    for (int kt = 0; kt < 16; ++kt) {
        int idx = ((W * 8 + v) * 16 + kt) * 64 + l;
        w1hR[kt] = w1h[idx];
        w1lR[kt] = w1l[idx];
    }

    const int row = tid >> 5;
    const int ul = tid & 31;
    const int ug = 32 * W + ul;
    float xwi[4], b1v[4];
#pragma unroll
    for (int gt = 0; gt < 4; ++gt) {
        xwi[gt] = xw0g[(g16 + row) * 1024 + gt * 256 + ug];
        b1v[gt] = b1sum[gt * 256 + ug];
    }
    float c0 = 0.f, c1 = 0.f, hs = 0.f;

    const float sb1a = sb1[l], sb1b = sb1[64 + l];
    const float sga = sg[l], sgb = sg[64 + l];
    const float sbea = sbe[l], sbeb = sbe[64 + l];
    const float sw2a = sW2[l], sw2b = sW2[64 + l];
    const float sb2v = sb2[0];

    unsigned* h0buf[2] = {hbuf + HPLANE(gidx, 0, 0), hbuf + HPLANE(gidx, 0, 1)};
    unsigned* h1buf[2] = {hbuf + HPLANE(gidx, 1, 0), hbuf + HPLANE(gidx, 1, 1)};
    unsigned* fl0 = flags + FLG(0, gidx, W);
    unsigned* fl1 = flags + FLG(1, gidx, W);
    unsigned* fl0base = flags + FLG(0, gidx, 0);
    unsigned* fl1base = flags + FLG(1, gidx, 0);

    const int abase = ln16 * 1024;
    const int aswz = (ln16 & 7) << 4;
    const int kgo = kg * 16;
    const int gcol = (v >> 1) * 32 + (v & 1) * 16 + ln16;
    const int hprow = 2 * W + (v & 1);
    const int hpswz = (hprow & 7) << 4;
    const int kq = v >> 1;

    __syncthreads();

    for (int t = 0; t < TSTEPS; ++t) {
        const int cur = t & 1, prev = cur ^ 1;
        // 1. MV0: Whh0 @ h0(t-1)
        {
            f32x4 acc = {0.f, 0.f, 0.f, 0.f};
#pragma unroll
            for (int kt = 0; kt < 8; ++kt) {
                int aoff = abase + ((kt * 64 + kgo) ^ aswz);
                bf16x8 ahi = bcast16(*(const uint4*)(hhiB + aoff));
                bf16x8 alo = bcast16(*(const uint4*)(hloB + aoff));
                bf16x8 bh = bcast16(b0h[kt]);
                bf16x8 bl = bcast16(b0l[kt]);
                acc = MFMA(ahi, bh, acc);
                acc = MFMA(alo, bh, acc);
                acc = MFMA(ahi, bl, acc);
            }
#pragma unroll
            for (int r = 0; r < 4; ++r) gatesL[(kg * 4 + r) * 132 + gcol] = acc[r];
        }
        __syncthreads();  // B1
        // 2. UPD0 -> publish h0(t)
        {
            float i_ = gatesL[row * 132 + ul] + xwi[0];
            float f_ = gatesL[row * 132 + 32 + ul] + xwi[1];
            float g_ = gatesL[row * 132 + 64 + ul] + xwi[2];
            float o_ = gatesL[row * 132 + 96 + ul] + xwi[3];
            c0 = fsig(f_) * c0 + fsig(i_) * ftanh(g_);
            float h = fsig(o_) * ftanh(c0);
            unsigned short hh = f2bf(h);
            unsigned short ll = f2bf(h - bf2f(hh));
            astore(h0buf[cur] + row * 256 + ug, ((unsigned)hh << 16) | (unsigned)ll);
        }
        asm volatile("s_waitcnt vmcnt(0)" ::: "memory");
        __syncthreads();  // B2
        if (tid == 0) astore(fl0, (unsigned)(t + 1));
        // 3. wait fl1 >= t (aged ~a full step)
        {
            unsigned tgt = (unsigned)t;
            while (true) {
                unsigned val = (l < 8) ? aload(fl1base + l * 32) : tgt;
                if (__all((int)(val >= tgt))) break;
                __builtin_amdgcn_s_sleep(1);
            }
        }
        asm volatile("" ::: "memory");
        // 4. stage h1(t-1)
        {
            unsigned* src = h1buf[prev];
            for (int i = tid; i < 4096; i += 512) {
                int r_ = i >> 8, u_ = i & 255;
                unsigned val = aload(src + i);
                int off = r_ * 1024 + ((512 + 2 * u_) ^ ((r_ & 7) << 4));
                *(unsigned short*)(hhiB + off) = (unsigned short)(val >> 16);
                *(unsigned short*)(hloB + off) = (unsigned short)(val & 0xffffu);
            }
        }
        __syncthreads();  // B3
        // 5. MV1-partB (Whh1 @ h1(t-1)) + head partials — hides fl0 wait
        f32x4 acc1 = {0.f, 0.f, 0.f, 0.f};
#pragma unroll
        for (int kt = 8; kt < 16; ++kt) {
            int aoff = abase + ((kt * 64 + kgo) ^ aswz);
            bf16x8 ahi = bcast16(*(const uint4*)(hhiB + aoff));
            bf16x8 alo = bcast16(*(const uint4*)(hloB + aoff));
            bf16x8 bh = bcast16(w1hR[kt]);
            bf16x8 bl = bcast16(w1lR[kt]);
            acc1 = MFMA(ahi, bh, acc1);
            acc1 = MFMA(alo, bh, acc1);
            acc1 = MFMA(ahi, bl, acc1);
        }
        {
            float accA = 0.f, accB = 0.f;
            int hb = hprow * 1024;
#pragma unroll
            for (int kc = 0; kc < 8; ++kc) {
                int kb = kq * 64 + kc * 8;
                uint4 hi4 = *(const uint4*)(hhiB + hb + ((512 + 2 * kb) ^ hpswz));
                uint4 lo4 = *(const uint4*)(hloB + hb + ((512 + 2 * kb) ^ hpswz));
                int idx8 = kq * 8 + kc;
                uint4 wA4 = *(const uint4*)&sw1s[(idx8 * 128 + l) * 8];
                uint4 wB4 = *(const uint4*)&sw1s[(idx8 * 128 + 64 + l) * 8];
#pragma unroll
                for (int q = 0; q < 4; ++q) {
                    unsigned hw = ((const unsigned*)&hi4)[q];
                    unsigned lw = ((const unsigned*)&lo4)[q];
                    float he = u32lo(hw) + u32lo(lw);
                    float ho = u32hi(hw) + u32hi(lw);
                    unsigned wa = ((const unsigned*)&wA4)[q];
                    unsigned wb = ((const unsigned*)&wB4)[q];
                    accA = fmaf(u32lo(wa), he, accA);
                    accA = fmaf(u32hi(wa), ho, accA);
                    accB = fmaf(u32lo(wb), he, accB);
                    accB = fmaf(u32hi(wb), ho, accB);
                }
            }
            ppart[(v & 1) * 512 + kq * 128 + l] = accA;
            ppart[(v & 1) * 512 + kq * 128 + 64 + l] = accB;
        }
        // 6. wait fl0 >= t+1 (mostly hidden behind step 5)
        {
            unsigned tgt = (unsigned)(t + 1);
            while (true) {
                unsigned val = (l < 8) ? aload(fl0base + l * 32) : tgt;
                if (__all((int)(val >= tgt))) break;
                __builtin_amdgcn_s_sleep(1);
            }
        }
        asm volatile("" ::: "memory");
        // 7. stage h0(t)
        {
            unsigned* src = h0buf[cur];
            for (int i = tid; i < 4096; i += 512) {
                int r_ = i >> 8, u_ = i & 255;
                unsigned val = aload(src + i);
                int off = r_ * 1024 + ((2 * u_) ^ ((r_ & 7) << 4));
                *(unsigned short*)(hhiB + off) = (unsigned short)(val >> 16);
                *(unsigned short*)(hloB + off) = (unsigned short)(val & 0xffffu);
            }
        }
        __syncthreads();  // B4
        // 8. MV1-partA (Wih1 @ h0(t))
        {
#pragma unroll
            for (int kt = 0; kt < 8; ++kt) {
                int aoff = abase + ((kt * 64 + kgo) ^ aswz);
                bf16x8 ahi = bcast16(*(const uint4*)(hhiB + aoff));
                bf16x8 alo = bcast16(*(const uint4*)(hloB + aoff));
                bf16x8 bh = bcast16(w1hR[kt]);
                bf16x8 bl = bcast16(w1lR[kt]);
                acc1 = MFMA(ahi, bh, acc1);
                acc1 = MFMA(alo, bh, acc1);
                acc1 = MFMA(ahi, bl, acc1);
            }
#pragma unroll
            for (int r = 0; r < 4; ++r) gatesL[(kg * 4 + r) * 132 + gcol] = acc1[r];
        }
        __syncthreads();  // B5
        // 9. UPD1 -> publish h1(t)
        {
            float i_ = gatesL[row * 132 + ul] + b1v[0];
            float f_ = gatesL[row * 132 + 32 + ul] + b1v[1];
            float g_ = gatesL[row * 132 + 64 + ul] + b1v[2];
            float o_ = gatesL[row * 132 + 96 + ul] + b1v[3];
            c1 = fsig(f_) * c1 + fsig(i_) * ftanh(g_);
            float h = fsig(o_) * ftanh(c1);
            hs += h;
            unsigned short hh = f2bf(h);
            unsigned short ll = f2bf(h - bf2f(hh));
            astore(h1buf[cur] + row * 256 + ug, ((unsigned)hh << 16) | (unsigned)ll);
        }
        asm volatile("s_waitcnt vmcnt(0)" ::: "memory");
        __syncthreads();  // B6
        if (tid == 0) astore(fl1, (unsigned)(t + 1));
        // 10. head finish -> base(t-1)
        if (t > 0 && v < 2) {
            float sA = sb1a, sB = sb1b;
#pragma unroll
            for (int q = 0; q < 4; ++q) {
                sA += ppart[v * 512 + q * 128 + l];
                sB += ppart[v * 512 + q * 128 + 64 + l];
            }
            float ssum = sA + sB, ssq = sA * sA + sB * sB;
#pragma unroll
            for (int o = 1; o < 64; o <<= 1) { ssum += __shfl_xor(ssum, o); ssq += __shfl_xor(ssq, o); }
            float m = ssum * (1.f / 128.f);
            float var = ssq * (1.f / 128.f) - m * m;
            float rstd = rsqrtf(var + EPSF);
            float p0 = fleaky((sA - m) * rstd * sga + sbea);
            float p1 = fleaky((sB - m) * rstd * sgb + sbeb);
            float q = p0 * sw2a + p1 * sw2b;
#pragma unroll
            for (int o = 1; o < 64; o <<= 1) q += __shfl_xor(q, o);
            if (l == 0) base_out[(g16 + 2 * W + v) * TSTEPS + (t - 1)] = ftanh(q + sb2v);
        }
    }
    // epilogue: base(1919)
    {
        unsigned tgt = (unsigned)TSTEPS;
        while (true) {
            unsigned val = (l < 8) ? aload(fl1base + l * 32) : tgt;
            if (__all((int)(val >= tgt))) break;
            __builtin_amdgcn_s_sleep(1);
        }
    }
    asm volatile("" ::: "memory");
    {
        unsigned* src = h1buf[(TSTEPS - 1) & 1];
        for (int i = tid; i < 4096; i += 512) {
            int r_ = i >> 8, u_ = i & 255;
            unsigned val = aload(src + i);
            int off = r_ * 1024 + ((512 + 2 * u_) ^ ((r_ & 7) << 4));
            *(unsigned short*)(hhiB + off) = (unsigned short)(val >> 16);
            *(unsigned short*)(hloB + off) = (unsigned short)(val & 0xffffu);
        }
    }
    __syncthreads();
    {
        float accA = 0.f, accB = 0.f;
        int hb = hprow * 1024;
#pragma unroll
        for (int kc = 0; kc < 8; ++kc) {
            int kb = kq * 64 + kc * 8;
            uint4 hi4 = *(const uint4*)(hhiB + hb + ((512 + 2 * kb) ^ hpswz));
            uint4 lo4 = *(const uint4*)(hloB + hb + ((512 + 2 * kb) ^ hpswz));
            int idx8 = kq * 8 + kc;
            uint4 wA4 = *(const uint4*)&sw1s[(idx8 * 128 + l) * 8];
            uint4 wB4 = *(const uint4*)&sw1s[(idx8 * 128 + 64 + l) * 8];
#pragma unroll
            for (int q = 0; q < 4; ++q) {
                unsigned hw = ((const unsigned*)&hi4)[q];
                unsigned lw = ((const unsigned*)&lo4)[q];
                float he = u32lo(hw) + u32lo(lw);
                float ho = u32hi(hw) + u32hi(lw);
                unsigned wa = ((const unsigned*)&wA4)[q];
                unsigned wb = ((const unsigned*)&wB4)[q];
                accA = fmaf(u32lo(wa), he, accA);
                accA = fmaf(u32hi(wa), ho, accA);
                accB = fmaf(u32lo(wb), he, accB);
                accB = fmaf(u32hi(wb), ho, accB);
            }
        }
        ppart[(v & 1) * 512 + kq * 128 + l] = accA;
        ppart[(v & 1) * 512 + kq * 128 + 64 + l] = accB;
    }
    __syncthreads();
    if (v < 2) {
        float sA = sb1a, sB = sb1b;
#pragma unroll
        for (int q = 0; q < 4; ++q) {
            sA += ppart[v * 512 + q * 128 + l];
            sB += ppart[v * 512 + q * 128 + 64 + l];
        }
        float ssum = sA + sB, ssq = sA * sA + sB * sB;
#pragma unroll
        for (int o = 1; o < 64; o <<= 1) { ssum += __shfl_xor(ssum, o); ssq += __shfl_xor(ssq, o); }
        float m = ssum * (1.f / 128.f);
        float var = ssq * (1.f / 128.f) - m * m;
        float rstd = rsqrtf(var + EPSF);
        float p0 = fleaky((sA - m) * rstd * sga + sbea);
        float p1 = fleaky((sB - m) * rstd * sgb + sbeb);
        float q = p0 * sw2a + p1 * sw2b;
#pragma unroll
        for (int o = 1; o < 64; o <<= 1) q += __shfl_xor(q, o);
        if (l == 0) base_out[(g16 + 2 * W + v) * TSTEPS + (TSTEPS - 1)] = ftanh(q + sb2v);
    }
    hsum_out[(g16 + row) * HIDN + ug] = hs;
}

__global__ void out_kernel(const float* __restrict__ hsum, const float* __restrict__ oW1,
                           const float* __restrict__ ob1, const float* __restrict__ og,
                           const float* __restrict__ obe, const float* __restrict__ oW2,
                           const float* __restrict__ ob2, const float* __restrict__ base,
                           const int* __restrict__ labels, const float* __restrict__ stress_w,
                           const float* __restrict__ amu_w, const float* __restrict__ amu_b,
                           float* __restrict__ out) {
    int b = blockIdx.x;
    int tid = threadIdx.x;
    int lane = tid & 63, wv = tid >> 6;
    __shared__ float havg[256];
    __shared__ float red[8];
    __shared__ float params[3];
    __shared__ float e_row[TSTEPS];
    havg[tid] = hsum[b * 256 + tid] * (1.f / (float)TSTEPS);
    __syncthreads();
    float d1 = 0.f;
    if (tid < 128) {
        d1 = ob1[tid];
        for (int k = 0; k < 256; ++k) d1 += havg[k] * oW1[tid * 256 + k];
    }
    float s = d1, s2 = d1 * d1;
    for (int o = 1; o < 64; o <<= 1) { s += __shfl_xor(s, o); s2 += __shfl_xor(s2, o); }
    if (lane == 0 && wv < 2) { red[wv] = s; red[2 + wv] = s2; }
    __syncthreads();
    float m = (red[0] + red[1]) * (1.f / 128.f);
    float var = (red[2] + red[3]) * (1.f / 128.f) - m * m;
    float rstd = rsqrtf(var + EPSF);
    float p = 0.f;
    if (tid < 128) p = fleaky((d1 - m) * rstd * og[tid] + obe[tid]);
    float q0 = tid < 128 ? p * oW2[0 * 128 + tid] : 0.f;
    float q1 = tid < 128 ? p * oW2[1 * 128 + tid] : 0.f;
    float q2 = tid < 128 ? p * oW2[2 * 128 + tid] : 0.f;
    for (int o = 1; o < 64; o <<= 1) {
        q0 += __shfl_xor(q0, o); q1 += __shfl_xor(q1, o); q2 += __shfl_xor(q2, o);
    }
    __syncthreads();
    if (lane == 0 && wv < 2) { red[wv] = q0; red[2 + wv] = q1; red[4 + wv] = q2; }
    __syncthreads();
    if (tid == 0) {
        float op0 = red[0] + red[1] + ob2[0];
        float op1 = red[2] + red[3] + ob2[1];
        float op2 = red[4] + red[5] + ob2[2];
        params[0] = 0.23f + 0.04f * ftanh(op0);
        params[1] = 2.0f + 1.5f * ftanh(op1);
        params[2] = 3.14159265358979f * fsig(op2);
    }
    __syncthreads();
    float freq = params[0], amp = params[1], ph = params[2];
    for (int t = tid; t < TSTEPS; t += 256) {
        float x = freq * ((float)TSTEPS * (float)t / (float)(TSTEPS - 1));
        x -= floorf(x);
        float osc = amp * __sinf(6.28318530717958647f * x + ph);
        e_row[t] = 0.6f * base[b * TSTEPS + t] + 0.4f * osc;
    }
    __syncthreads();
    int lab = labels[b];
    float sw = stress_w[0];
    float w0 = amu_w[0], w1 = amu_w[1], w2 = amu_w[2], ab = amu_b[0];
    for (int t = tid; t < TSTEPS; t += 256) {
        float e = e_row[t];
        float r;
        if (lab == 1) r = e;
        else if (lab == 2) r = sw * e;
        else if (lab == 3) {
            float em = t > 0 ? e_row[t - 1] : 0.f;
            float ep = t < TSTEPS - 1 ? e_row[t + 1] : 0.f;
            r = w0 * em + w1 * e + w2 * ep + ab;
        } else r = 0.f;
        out[b * TSTEPS + t] = r;
    }
}

extern "C" void kernel_launch(void* const* d_in, const int* in_sizes, int n_in,
                              void* d_out, int out_size, void* d_ws, size_t ws_size,
                              hipStream_t stream) {
    (void)in_sizes; (void)n_in; (void)out_size; (void)ws_size;
    const float* z      = (const float*)d_in[0];
    const int* labels   = (const int*)d_in[1];
    const float* emb_W  = (const float*)d_in[2];
    const float* np_W   = (const float*)d_in[3];
    const float* np_b   = (const float*)d_in[4];
    const float* np_g   = (const float*)d_in[5];
    const float* np_be  = (const float*)d_in[6];
    const float* Wih0   = (const float*)d_in[7];
    const float* Whh0   = (const float*)d_in[8];
    const float* bih0   = (const float*)d_in[9];
    const float* bhh0   = (const float*)d_in[10];
    const float* Wih1   = (const float*)d_in[11];
    const float* Whh1   = (const float*)d_in[12];
    const float* bih1   = (const float*)d_in[13];
    const float* bhh1   = (const float*)d_in[14];
    const float* oW1    = (const float*)d_in[15];
    const float* ob1    = (const float*)d_in[16];
    const float* og     = (const float*)d_in[17];
    const float* obe    = (const float*)d_in[18];
    const float* oW2    = (const float*)d_in[19];
    const float* ob2    = (const float*)d_in[20];
    const float* sW1    = (const float*)d_in[21];
    const float* sb1    = (const float*)d_in[22];
    const float* sg     = (const float*)d_in[23];
    const float* sbe    = (const float*)d_in[24];
    const float* sW2    = (const float*)d_in[25];
    const float* sb2    = (const float*)d_in[26];
    const float* stressw= (const float*)d_in[27];
    const float* amu_w  = (const float*)d_in[28];
    const float* amu_b  = (const float*)d_in[29];
    float* out = (float*)d_out;

    uint8_t* ws = (uint8_t*)d_ws;
    size_t off = 0;
    unsigned short* whh0h = (unsigned short*)(ws + off); off += (size_t)1024 * 256 * 2;
    unsigned short* whh0l = (unsigned short*)(ws + off); off += (size_t)1024 * 256 * 2;
    unsigned short* w1h   = (unsigned short*)(ws + off); off += (size_t)1024 * 512 * 2;
    unsigned short* w1l   = (unsigned short*)(ws + off); off += (size_t)1024 * 512 * 2;
    unsigned short* sw1k8 = (unsigned short*)(ws + off); off += (size_t)256 * 128 * 2;
    float* Wih0T4 = (float*)(ws + off); off += (size_t)1024 * 512 * 4;
    float* x_const= (float*)(ws + off); off += (size_t)NB * 512 * 4;
    float* xw0    = (float*)(ws + off); off += (size_t)NB * 1024 * 4;
    float* b1sum  = (float*)(ws + off); off += (size_t)1024 * 4;
    float* hsum   = (float*)(ws + off); off += (size_t)NB * 256 * 4;
    float* basef  = (float*)(ws + off); off += (size_t)NB * TSTEPS * 4;
    off = (off + 255) & ~(size_t)255;
    unsigned* hbuf = (unsigned*)(ws + off); off += (size_t)131072 * 4;
    unsigned* flags= (unsigned*)(ws + off); off += (size_t)4096 * 4;

    init_sync<<<512, 256, 0, stream>>>(hbuf, flags);
    pack_bfrag_sliced<<<1024, 256, 0, stream>>>(Whh0, nullptr, 256, 0, whh0h, whh0l);
    pack_bfrag_sliced<<<2048, 256, 0, stream>>>(Wih1, Whh1, 256, 256, w1h, w1l);
    pack_sw1k8<<<128, 256, 0, stream>>>(sW1, sw1k8);
    pack4T<<<2048, 256, 0, stream>>>(Wih0, 1024, 512, Wih0T4);
    prep_b1<<<4, 256, 0, stream>>>(bih1, bhh1, b1sum);

    np_head<<<NB, 256, 0, stream>>>(z, labels, emb_W, np_W, np_b, np_g, np_be, x_const);
    xw0_kernel<<<NB, 1024, 0, stream>>>(x_const, (const float4*)Wih0T4, bih0, bhh0, xw0);
    lstm_coop<<<64, 512, 110848, stream>>>((const uint4*)whh0h, (const uint4*)whh0l,
                                           (const uint4*)w1h, (const uint4*)w1l,
                                           sw1k8, xw0, b1sum, sb1, sg, sbe, sW2, sb2,
                                           hbuf, flags, basef, hsum);
    out_kernel<<<NB, 256, 0, stream>>>(hsum, oW1, ob1, og, obe, oW2, ob2, basef, labels,
                                       stressw, amu_w, amu_b, out);
}

// Round 12
// 25717.987 us; speedup vs baseline: 1.6481x; 1.0410x over previous
//
#include <hip/hip_runtime.h>

#define TSTEPS 1920
#define NB 128
#define HIDN 256
#define LATN 128
#define EPSF 1e-5f

typedef __attribute__((ext_vector_type(8))) short bf16x8;
typedef __attribute__((ext_vector_type(4))) float f32x4;

__device__ __forceinline__ unsigned short f2bf(float x) {
    unsigned u = __builtin_bit_cast(unsigned, x);
    unsigned r = (u + 0x7fffu + ((u >> 16) & 1u)) >> 16;
    return (unsigned short)r;
}
__device__ __forceinline__ float bf2f(unsigned short h) {
    unsigned u = ((unsigned)h) << 16;
    return __builtin_bit_cast(float, u);
}
__device__ __forceinline__ float u32lo(unsigned w) {
    return __builtin_bit_cast(float, w << 16);
}
__device__ __forceinline__ float u32hi(unsigned w) {
    return __builtin_bit_cast(float, w & 0xFFFF0000u);
}
__device__ __forceinline__ float fsig(float x) {
    float e = __expf(-fabsf(x));
    float s = 1.f / (1.f + e);
    return x >= 0.f ? s : 1.f - s;
}
__device__ __forceinline__ float ftanh(float x) {
    float e = __expf(-2.f * fabsf(x));
    float r = (1.f - e) / (1.f + e);
    return x >= 0.f ? r : -r;
}
__device__ __forceinline__ float fleaky(float x) { return x > 0.f ? x : 0.2f * x; }
__device__ __forceinline__ bf16x8 bcast16(uint4 v) { return __builtin_bit_cast(bf16x8, v); }

__device__ __forceinline__ unsigned aload(const unsigned* p) {
    return __hip_atomic_load(p, __ATOMIC_RELAXED, __HIP_MEMORY_SCOPE_AGENT);
}
__device__ __forceinline__ unsigned long long aload64(const unsigned long long* p) {
    return __hip_atomic_load(p, __ATOMIC_RELAXED, __HIP_MEMORY_SCOPE_AGENT);
}
__device__ __forceinline__ void astore(unsigned* p, unsigned v) {
    __hip_atomic_store(p, v, __ATOMIC_RELAXED, __HIP_MEMORY_SCOPE_AGENT);
}

#define MFMA(a, b, c) __builtin_amdgcn_mfma_f32_16x16x32_bf16((a), (b), (c), 0, 0, 0)

#define FLG(ph, g, s) (((ph) * 8 + (g)) * 8 + (s)) * 32
#define HPLANE(g, layer, buf) (((g) * 2 + (layer)) * 2 + (buf)) * 4096

__global__ void init_sync(unsigned* hbuf, unsigned* flags) {
    int i = blockIdx.x * 256 + threadIdx.x;
    if (i < 131072) hbuf[i] = 0u;
    if (i < 4096) flags[i] = 0u;
}

// ---- pack W [1024][KA+KB] -> sliced MFMA B-frag order, hi/lo bf16 ----
__global__ void pack_bfrag_sliced(const float* __restrict__ A, const float* __restrict__ Bsrc,
                                  int KA, int KB,
                                  unsigned short* __restrict__ hi, unsigned short* __restrict__ lo) {
    int e = blockIdx.x * 256 + threadIdx.x;
    int K = KA + KB;
    int KT = K >> 5;
    if (e >= 1024 * K) return;
    int j = e & 7;
    int l = (e >> 3) & 63;
    int r = e >> 9;
    int kt = r % KT;
    int r2 = r / KT;
    int v = r2 & 7;
    int w = r2 >> 3;
    int n = (v >> 1) * 256 + 32 * w + 16 * (v & 1) + (l & 15);
    int k = kt * 32 + (l >> 4) * 8 + j;
    float val = (k < KA) ? A[n * KA + k] : Bsrc[n * KB + (k - KA)];
    unsigned short h = f2bf(val);
    hi[e] = h;
    lo[e] = f2bf(val - bf2f(h));
}

// ---- pack sW1 [128][256] -> [k/8][j][8] bf16 ----
__global__ void pack_sw1k8(const float* __restrict__ sW1, unsigned short* __restrict__ out) {
    int e = blockIdx.x * 256 + threadIdx.x;
    if (e >= 256 * 128) return;
    int j = e & 127, k = e >> 7;
    out[((k >> 3) * 128 + j) * 8 + (k & 7)] = f2bf(sW1[j * 256 + k]);
}

__global__ void pack4T(const float* __restrict__ W, int N, int K, float* __restrict__ out) {
    int e = blockIdx.x * 256 + threadIdx.x;
    if (e >= N * K) return;
    int j = e & 3;
    int rest = e >> 2;
    int n = rest % N;
    int k4 = rest / N;
    out[e] = W[n * K + 4 * k4 + j];
}

__global__ void prep_b1(const float* __restrict__ bih1, const float* __restrict__ bhh1,
                        float* __restrict__ b1sum) {
    int i = blockIdx.x * 256 + threadIdx.x;
    if (i < 1024) b1sum[i] = bih1[i] + bhh1[i];
}

__global__ void np_head(const float* __restrict__ z, const int* __restrict__ labels,
                        const float* __restrict__ emb_W, const float* __restrict__ np_W,
                        const float* __restrict__ np_b, const float* __restrict__ np_g,
                        const float* __restrict__ np_be, float* __restrict__ x_const) {
    int b = blockIdx.x;
    int j = threadIdx.x;
    __shared__ float xc[LATN + HIDN];
    __shared__ float red[8];
    int lab = labels[b];
    if (j < LATN) xc[j] = z[b * LATN + j];
    float e = emb_W[lab * HIDN + j];
    xc[LATN + j] = e;
    __syncthreads();
    float d = np_b[j];
    for (int k = 0; k < LATN + HIDN; ++k) d += xc[k] * np_W[j * (LATN + HIDN) + k];
    int lane = j & 63, wv = j >> 6;
    float s = d, s2 = d * d;
    for (int o = 1; o < 64; o <<= 1) { s += __shfl_xor(s, o); s2 += __shfl_xor(s2, o); }
    if (lane == 0) { red[wv] = s; red[4 + wv] = s2; }
    __syncthreads();
    float S = red[0] + red[1] + red[2] + red[3];
    float S2 = red[4] + red[5] + red[6] + red[7];
    float m = S * (1.f / 256.f);
    float var = S2 * (1.f / 256.f) - m * m;
    float h = fleaky((d - m) * rsqrtf(var + EPSF) * np_g[j] + np_be[j]);
    x_const[b * 512 + j] = h;
    x_const[b * 512 + 256 + j] = e;
}

__global__ void __launch_bounds__(1024) xw0_kernel(const float* __restrict__ x_const,
                                                   const float4* __restrict__ Wih0T4,
                                                   const float* __restrict__ bih0,
                                                   const float* __restrict__ bhh0,
                                                   float* __restrict__ xw0) {
    int b = blockIdx.x;
    int g = threadIdx.x;
    __shared__ float xc[512];
    if (g < 512) xc[g] = x_const[b * 512 + g];
    __syncthreads();
    const float4* xc4 = (const float4*)xc;
    float4 acc = {0.f, 0.f, 0.f, 0.f};
#pragma unroll 8
    for (int k4 = 0; k4 < 128; ++k4) {
        float4 w = Wih0T4[k4 * 1024 + g];
        float4 x = xc4[k4];
        acc.x = fmaf(w.x, x.x, acc.x);
        acc.y = fmaf(w.y, x.y, acc.y);
        acc.z = fmaf(w.z, x.z, acc.z);
        acc.w = fmaf(w.w, x.w, acc.w);
    }
    xw0[b * 1024 + g] = bih0[g] + bhh0[g] + ((acc.x + acc.y) + (acc.z + acc.w));
}

// ==== main recurrent kernel: 64 blocks (8 groups x 8 slices) x 512 thr ====
// R5 schedule; waits executed by wave 0 only (8 pollers/block, not 64) +
// release barrier — cuts agent-scope flag-poll traffic 8x.
__global__ void __launch_bounds__(512, 2) lstm_coop(
    const uint4* __restrict__ whh0h, const uint4* __restrict__ whh0l,
    const uint4* __restrict__ w1h, const uint4* __restrict__ w1l,
    const unsigned short* __restrict__ sw1k8_g, const float* __restrict__ xw0g,
    const float* __restrict__ b1sum, const float* __restrict__ sb1,
    const float* __restrict__ sg, const float* __restrict__ sbe,
    const float* __restrict__ sW2, const float* __restrict__ sb2,
    unsigned* __restrict__ hbuf, unsigned* __restrict__ flags,
    float* __restrict__ base_out, float* __restrict__ hsum_out) {
    extern __shared__ char smem[];
    unsigned short* hhi = (unsigned short*)smem;
    unsigned short* hlo = (unsigned short*)(smem + 16384);
    unsigned short* sw1s = (unsigned short*)(smem + 32768);
    float* gatesL = (float*)(smem + 98304);
    float* ppart = (float*)(smem + 106752);
    char* hhiB = smem;
    char* hloB = smem + 16384;

    const int gidx = blockIdx.x & 7;
    const int W = blockIdx.x >> 3;
    const int g16 = gidx * 16;
    const int tid = threadIdx.x;
    const int l = tid & 63;
    const int v = tid >> 6;
    const int ln16 = l & 15;
    const int kg = l >> 4;

    for (int i = tid; i < 256 * 128; i += 512) sw1s[i] = sw1k8_g[i];
    for (int i = tid; i < 8192; i += 512) { hhi[i] = 0; hlo[i] = 0; }

    uint4 b0h[8], b0l[8];
#pragma unroll
    for (int kt = 0; kt < 8; ++kt) {
        int idx = ((W * 8 + v) * 8 + kt) * 64 + l;
        b0h[kt] = whh0h[idx];
        b0l[kt] = whh0l[idx];
    }
    uint4 w1hR[16], w1lR[16];
#pragma unroll
    for (int kt = 0; kt < 16; ++kt) {
        int idx = ((W * 8 + v) * 16 + kt) * 64 + l;
        w1hR[kt] = w1h[idx];
        w1lR[kt] = w1l[idx];
    }

    const int row = tid >> 5;
    const int ul = tid & 31;
    const int ug = 32 * W + ul;
    float xwi[4], b1v[4];
#pragma unroll
    for (int gt = 0; gt < 4; ++gt) {
        xwi[gt] = xw0g[(g16 + row) * 1024 + gt * 256 + ug];
        b1v[gt] = b1sum[gt * 256 + ug];
    }
    float c0 = 0.f, c1 = 0.f, hs = 0.f;

    const float sb1a = sb1[l], sb1b = sb1[64 + l];
    const float sga = sg[l], sgb = sg[64 + l];
    const float sbea = sbe[l], sbeb = sbe[64 + l];
    const float sw2a = sW2[l], sw2b = sW2[64 + l];
    const float sb2v = sb2[0];

    unsigned* h0buf[2] = {hbuf + HPLANE(gidx, 0, 0), hbuf + HPLANE(gidx, 0, 1)};
    unsigned* h1buf[2] = {hbuf + HPLANE(gidx, 1, 0), hbuf + HPLANE(gidx, 1, 1)};
    unsigned* fl0 = flags + FLG(0, gidx, W);
    unsigned* fl1 = flags + FLG(1, gidx, W);
    unsigned* fl0base = flags + FLG(0, gidx, 0);
    unsigned* fl1base = flags + FLG(1, gidx, 0);

    const int abase = ln16 * 1024;
    const int aswz = (ln16 & 7) << 4;
    const int kgo = kg * 16;
    const int gcol = (v >> 1) * 32 + (v & 1) * 16 + ln16;
    const int hprow = 2 * W + (v & 1);
    const int hpswz = (hprow & 7) << 4;
    const int kq = v >> 1;

    // wave-0-only wait, then release barrier (others park at __syncthreads)
#define WAIT1(BASE, tgtv)                                                        \
    if (v == 0) {                                                                \
        unsigned tgt_ = (unsigned)(tgtv);                                        \
        while (true) {                                                           \
            unsigned val_ = (l < 8) ? aload((BASE) + l * 32) : tgt_;             \
            if (__all((int)(val_ >= tgt_))) break;                               \
            __builtin_amdgcn_s_sleep(1);                                         \
        }                                                                        \
    }                                                                            \
    __syncthreads();                                                             \
    asm volatile("" ::: "memory");

    __syncthreads();

    for (int t = 0; t < TSTEPS; ++t) {
        const int cur = t & 1, prev = cur ^ 1;
        // 1. MV0: Whh0 @ h0(t-1)
        {
            f32x4 acc = {0.f, 0.f, 0.f, 0.f};
#pragma unroll
            for (int kt = 0; kt < 8; ++kt) {
                int aoff = abase + ((kt * 64 + kgo) ^ aswz);
                bf16x8 ahi = bcast16(*(const uint4*)(hhiB + aoff));
                bf16x8 alo = bcast16(*(const uint4*)(hloB + aoff));
                bf16x8 bh = bcast16(b0h[kt]);
                bf16x8 bl = bcast16(b0l[kt]);
                acc = MFMA(ahi, bh, acc);
                acc = MFMA(alo, bh, acc);
                acc = MFMA(ahi, bl, acc);
            }
#pragma unroll
            for (int r = 0; r < 4; ++r) gatesL[(kg * 4 + r) * 132 + gcol] = acc[r];
        }
        __syncthreads();  // B1
        // 2. UPD0 -> publish h0(t)
        {
            float i_ = gatesL[row * 132 + ul] + xwi[0];
            float f_ = gatesL[row * 132 + 32 + ul] + xwi[1];
            float g_ = gatesL[row * 132 + 64 + ul] + xwi[2];
            float o_ = gatesL[row * 132 + 96 + ul] + xwi[3];
            c0 = fsig(f_) * c0 + fsig(i_) * ftanh(g_);
            float h = fsig(o_) * ftanh(c0);
            unsigned short hh = f2bf(h);
            unsigned short ll = f2bf(h - bf2f(hh));
            astore(h0buf[cur] + row * 256 + ug, ((unsigned)hh << 16) | (unsigned)ll);
        }
        asm volatile("s_waitcnt vmcnt(0)" ::: "memory");
        __syncthreads();  // B2
        if (tid == 0) astore(fl0, (unsigned)(t + 1));
        // 3. wait fl1 >= t (aged ~a full step; wave0 polls)
        WAIT1(fl1base, t);
        // 4. stage h1(t-1)
        {
            unsigned* src = h1buf[prev];
            for (int i = tid; i < 4096; i += 512) {
                int r_ = i >> 8, u_ = i & 255;
                unsigned val = aload(src + i);
                int off = r_ * 1024 + ((512 + 2 * u_) ^ ((r_ & 7) << 4));
                *(unsigned short*)(hhiB + off) = (unsigned short)(val >> 16);
                *(unsigned short*)(hloB + off) = (unsigned short)(val & 0xffffu);
            }
        }
        __syncthreads();  // B3
        // 5. MV1-partB (Whh1 @ h1(t-1)) + head partials — ages fl0
        f32x4 acc1 = {0.f, 0.f, 0.f, 0.f};
#pragma unroll
        for (int kt = 8; kt < 16; ++kt) {
            int aoff = abase + ((kt * 64 + kgo) ^ aswz);
            bf16x8 ahi = bcast16(*(const uint4*)(hhiB + aoff));
            bf16x8 alo = bcast16(*(const uint4*)(hloB + aoff));
            bf16x8 bh = bcast16(w1hR[kt]);
            bf16x8 bl = bcast16(w1lR[kt]);
            acc1 = MFMA(ahi, bh, acc1);
            acc1 = MFMA(alo, bh, acc1);
            acc1 = MFMA(ahi, bl, acc1);
        }
        {
            float accA = 0.f, accB = 0.f;
            int hb = hprow * 1024;
#pragma unroll
            for (int kc = 0; kc < 8; ++kc) {
                int kb = kq * 64 + kc * 8;
                uint4 hi4 = *(const uint4*)(hhiB + hb + ((512 + 2 * kb) ^ hpswz));
                uint4 lo4 = *(const uint4*)(hloB + hb + ((512 + 2 * kb) ^ hpswz));
                int idx8 = kq * 8 + kc;
                uint4 wA4 = *(const uint4*)&sw1s[(idx8 * 128 + l) * 8];
                uint4 wB4 = *(const uint4*)&sw1s[(idx8 * 128 + 64 + l) * 8];
#pragma unroll
                for (int q = 0; q < 4; ++q) {
                    unsigned hw = ((const unsigned*)&hi4)[q];
                    unsigned lw = ((const unsigned*)&lo4)[q];
                    float he = u32lo(hw) + u32lo(lw);
                    float ho = u32hi(hw) + u32hi(lw);
                    unsigned wa = ((const unsigned*)&wA4)[q];
                    unsigned wb = ((const unsigned*)&wB4)[q];
                    accA = fmaf(u32lo(wa), he, accA);
                    accA = fmaf(u32hi(wa), ho, accA);
                    accB = fmaf(u32lo(wb), he, accB);
                    accB = fmaf(u32hi(wb), ho, accB);
                }
            }
            ppart[(v & 1) * 512 + kq * 128 + l] = accA;
            ppart[(v & 1) * 512 + kq * 128 + 64 + l] = accB;
        }
        // 6. wait fl0 >= t+1 (aged by step 5; wave0 polls)
        WAIT1(fl0base, t + 1);
        // 7. stage h0(t)
        {
            unsigned* src = h0buf[cur];
            for (int i = tid; i < 4096; i += 512) {
                int r_ = i >> 8, u_ = i & 255;
                unsigned val = aload(src + i);
                int off = r_ * 1024 + ((2 * u_) ^ ((r_ & 7) << 4));
                *(unsigned short*)(hhiB + off) = (unsigned short)(val >> 16);
                *(unsigned short*)(hloB + off) = (unsigned short)(val & 0xffffu);
            }
        }
        __syncthreads();  // B4
        // 8. MV1-partA (Wih1 @ h0(t))
        {
#pragma unroll
            for (int kt = 0; kt < 8; ++kt) {
                int aoff = abase + ((kt * 64 + kgo) ^ aswz);
                bf16x8 ahi = bcast16(*(const uint4*)(hhiB + aoff));
                bf16x8 alo = bcast16(*(const uint4*)(hloB + aoff));
                bf16x8 bh = bcast16(w1hR[kt]);
                bf16x8 bl = bcast16(w1lR[kt]);
                acc1 = MFMA(ahi, bh, acc1);
                acc1 = MFMA(alo, bh, acc1);
                acc1 = MFMA(ahi, bl, acc1);
            }
#pragma unroll
            for (int r = 0; r < 4; ++r) gatesL[(kg * 4 + r) * 132 + gcol] = acc1[r];
        }
        __syncthreads();  // B5
        // 9. UPD1 -> publish h1(t)
        {
            float i_ = gatesL[row * 132 + ul] + b1v[0];
            float f_ = gatesL[row * 132 + 32 + ul] + b1v[1];
            float g_ = gatesL[row * 132 + 64 + ul] + b1v[2];
            float o_ = gatesL[row * 132 + 96 + ul] + b1v[3];
            c1 = fsig(f_) * c1 + fsig(i_) * ftanh(g_);
            float h = fsig(o_) * ftanh(c1);
            hs += h;
            unsigned short hh = f2bf(h);
            unsigned short ll = f2bf(h - bf2f(hh));
            astore(h1buf[cur] + row * 256 + ug, ((unsigned)hh << 16) | (unsigned)ll);
        }
        asm volatile("s_waitcnt vmcnt(0)" ::: "memory");
        __syncthreads();  // B6
        if (tid == 0) astore(fl1, (unsigned)(t + 1));
        // 10. head finish -> base(t-1)
        if (t > 0 && v < 2) {
            float sA = sb1a, sB = sb1b;
#pragma unroll
            for (int q = 0; q < 4; ++q) {
                sA += ppart[v * 512 + q * 128 + l];
                sB += ppart[v * 512 + q * 128 + 64 + l];
            }
            float ssum = sA + sB, ssq = sA * sA + sB * sB;
#pragma unroll
            for (int o = 1; o < 64; o <<= 1) { ssum += __shfl_xor(ssum, o); ssq += __shfl_xor(ssq, o); }
            float m = ssum * (1.f / 128.f);
            float var = ssq * (1.f / 128.f) - m * m;
            float rstd = rsqrtf(var + EPSF);
            float p0 = fleaky((sA - m) * rstd * sga + sbea);
            float p1 = fleaky((sB - m) * rstd * sgb + sbeb);
            float q = p0 * sw2a + p1 * sw2b;
#pragma unroll
            for (int o = 1; o < 64; o <<= 1) q += __shfl_xor(q, o);
            if (l == 0) base_out[(g16 + 2 * W + v) * TSTEPS + (t - 1)] = ftanh(q + sb2v);
        }
    }
    // epilogue: base(1919)
    WAIT1(fl1base, TSTEPS);
    {
        unsigned* src = h1buf[(TSTEPS - 1) & 1];
        for (int i = tid; i < 4096; i += 512) {
            int r_ = i >> 8, u_ = i & 255;
            unsigned val = aload(src + i);
            int off = r_ * 1024 + ((512 + 2 * u_) ^ ((r_ & 7) << 4));
            *(unsigned short*)(hhiB + off) = (unsigned short)(val >> 16);
            *(unsigned short*)(hloB + off) = (unsigned short)(val & 0xffffu);
        }
    }
    __syncthreads();
    {
        float accA = 0.f, accB = 0.f;
        int hb = hprow * 1024;
#pragma unroll
        for (int kc = 0; kc < 8; ++kc) {
            int kb = kq * 64 + kc * 8;
            uint4 hi4 = *(const uint4*)(hhiB + hb + ((512 + 2 * kb) ^ hpswz));
            uint4 lo4 = *(const uint4*)(hloB + hb + ((512 + 2 * kb) ^ hpswz));
            int idx8 = kq * 8 + kc;
            uint4 wA4 = *(const uint4*)&sw1s[(idx8 * 128 + l) * 8];
            uint4 wB4 = *(const uint4*)&sw1s[(idx8 * 128 + 64 + l) * 8];
#pragma unroll
            for (int q = 0; q < 4; ++q) {
                unsigned hw = ((const unsigned*)&hi4)[q];
                unsigned lw = ((const unsigned*)&lo4)[q];
                float he = u32lo(hw) + u32lo(lw);
                float ho = u32hi(hw) + u32hi(lw);
                unsigned wa = ((const unsigned*)&wA4)[q];
                unsigned wb = ((const unsigned*)&wB4)[q];
                accA = fmaf(u32lo(wa), he, accA);
                accA = fmaf(u32hi(wa), ho, accA);
                accB = fmaf(u32lo(wb), he, accB);
                accB = fmaf(u32hi(wb), ho, accB);
            }
        }
        ppart[(v & 1) * 512 + kq * 128 + l] = accA;
        ppart[(v & 1) * 512 + kq * 128 + 64 + l] = accB;
    }
    __syncthreads();
    if (v < 2) {
        float sA = sb1a, sB = sb1b;
#pragma unroll
        for (int q = 0; q < 4; ++q) {
            sA += ppart[v * 512 + q * 128 + l];
            sB += ppart[v * 512 + q * 128 + 64 + l];
        }
        float ssum = sA + sB, ssq = sA * sA + sB * sB;
#pragma unroll
        for (int o = 1; o < 64; o <<= 1) { ssum += __shfl_xor(ssum, o); ssq += __shfl_xor(ssq, o); }
        float m = ssum * (1.f / 128.f);
        float var = ssq * (1.f / 128.f) - m * m;
        float rstd = rsqrtf(var + EPSF);
        float p0 = fleaky((sA - m) * rstd * sga + sbea);
        float p1 = fleaky((sB - m) * rstd * sgb + sbeb);
        float q = p0 * sw2a + p1 * sw2b;
#pragma unroll
        for (int o = 1; o < 64; o <<= 1) q += __shfl_xor(q, o);
        if (l == 0) base_out[(g16 + 2 * W + v) * TSTEPS + (TSTEPS - 1)] = ftanh(q + sb2v);
    }
    hsum_out[(g16 + row) * HIDN + ug] = hs;
#undef WAIT1
}

__global__ void out_kernel(const float* __restrict__ hsum, const float* __restrict__ oW1,
                           const float* __restrict__ ob1, const float* __restrict__ og,
                           const float* __restrict__ obe, const float* __restrict__ oW2,
                           const float* __restrict__ ob2, const float* __restrict__ base,
                           const int* __restrict__ labels, const float* __restrict__ stress_w,
                           const float* __restrict__ amu_w, const float* __restrict__ amu_b,
                           float* __restrict__ out) {
    int b = blockIdx.x;
    int tid = threadIdx.x;
    int lane = tid & 63, wv = tid >> 6;
    __shared__ float havg[256];
    __shared__ float red[8];
    __shared__ float params[3];
    __shared__ float e_row[TSTEPS];
    havg[tid] = hsum[b * 256 + tid] * (1.f / (float)TSTEPS);
    __syncthreads();
    float d1 = 0.f;
    if (tid < 128) {
        d1 = ob1[tid];
        for (int k = 0; k < 256; ++k) d1 += havg[k] * oW1[tid * 256 + k];
    }
    float s = d1, s2 = d1 * d1;
    for (int o = 1; o < 64; o <<= 1) { s += __shfl_xor(s, o); s2 += __shfl_xor(s2, o); }
    if (lane == 0 && wv < 2) { red[wv] = s; red[2 + wv] = s2; }
    __syncthreads();
    float m = (red[0] + red[1]) * (1.f / 128.f);
    float var = (red[2] + red[3]) * (1.f / 128.f) - m * m;
    float rstd = rsqrtf(var + EPSF);
    float p = 0.f;
    if (tid < 128) p = fleaky((d1 - m) * rstd * og[tid] + obe[tid]);
    float q0 = tid < 128 ? p * oW2[0 * 128 + tid] : 0.f;
    float q1 = tid < 128 ? p * oW2[1 * 128 + tid] : 0.f;
    float q2 = tid < 128 ? p * oW2[2 * 128 + tid] : 0.f;
    for (int o = 1; o < 64; o <<= 1) {
        q0 += __shfl_xor(q0, o); q1 += __shfl_xor(q1, o); q2 += __shfl_xor(q2, o);
    }
    __syncthreads();
    if (lane == 0 && wv < 2) { red[wv] = q0; red[2 + wv] = q1; red[4 + wv] = q2; }
    __syncthreads();
    if (tid == 0) {
        float op0 = red[0] + red[1] + ob2[0];
        float op1 = red[2] + red[3] + ob2[1];
        float op2 = red[4] + red[5] + ob2[2];
        params[0] = 0.23f + 0.04f * ftanh(op0);
        params[1] = 2.0f + 1.5f * ftanh(op1);
        params[2] = 3.14159265358979f * fsig(op2);
    }
    __syncthreads();
    float freq = params[0], amp = params[1], ph = params[2];
    for (int t = tid; t < TSTEPS; t += 256) {
        float x = freq * ((float)TSTEPS * (float)t / (float)(TSTEPS - 1));
        x -= floorf(x);
        float osc = amp * __sinf(6.28318530717958647f * x + ph);
        e_row[t] = 0.6f * base[b * TSTEPS + t] + 0.4f * osc;
    }
    __syncthreads();
    int lab = labels[b];
    float sw = stress_w[0];
    float w0 = amu_w[0], w1 = amu_w[1], w2 = amu_w[2], ab = amu_b[0];
    for (int t = tid; t < TSTEPS; t += 256) {
        float e = e_row[t];
        float r;
        if (lab == 1) r = e;
        else if (lab == 2) r = sw * e;
        else if (lab == 3) {
            float em = t > 0 ? e_row[t - 1] : 0.f;
            float ep = t < TSTEPS - 1 ? e_row[t + 1] : 0.f;
            r = w0 * em + w1 * e + w2 * ep + ab;
        } else r = 0.f;
        out[b * TSTEPS + t] = r;
    }
}

extern "C" void kernel_launch(void* const* d_in, const int* in_sizes, int n_in,
                              void* d_out, int out_size, void* d_ws, size_t ws_size,
                              hipStream_t stream) {
    (void)in_sizes; (void)n_in; (void)out_size; (void)ws_size;
    const float* z      = (const float*)d_in[0];
    const int* labels   = (const int*)d_in[1];
    const float* emb_W  = (const float*)d_in[2];
    const float* np_W   = (const float*)d_in[3];
    const float* np_b   = (const float*)d_in[4];
    const float* np_g   = (const float*)d_in[5];
    const float* np_be  = (const float*)d_in[6];
    const float* Wih0   = (const float*)d_in[7];
    const float* Whh0   = (const float*)d_in[8];
    const float* bih0   = (const float*)d_in[9];
    const float* bhh0   = (const float*)d_in[10];
    const float* Wih1   = (const float*)d_in[11];
    const float* Whh1   = (const float*)d_in[12];
    const float* bih1   = (const float*)d_in[13];
    const float* bhh1   = (const float*)d_in[14];
    const float* oW1    = (const float*)d_in[15];
    const float* ob1    = (const float*)d_in[16];
    const float* og     = (const float*)d_in[17];
    const float* obe    = (const float*)d_in[18];
    const float* oW2    = (const float*)d_in[19];
    const float* ob2    = (const float*)d_in[20];
    const float* sW1    = (const float*)d_in[21];
    const float* sb1    = (const float*)d_in[22];
    const float* sg     = (const float*)d_in[23];
    const float* sbe    = (const float*)d_in[24];
    const float* sW2    = (const float*)d_in[25];
    const float* sb2    = (const float*)d_in[26];
    const float* stressw= (const float*)d_in[27];
    const float* amu_w  = (const float*)d_in[28];
    const float* amu_b  = (const float*)d_in[29];
    float* out = (float*)d_out;

    uint8_t* ws = (uint8_t*)d_ws;
    size_t off = 0;
    unsigned short* whh0h = (unsigned short*)(ws + off); off += (size_t)1024 * 256 * 2;
    unsigned short* whh0l = (unsigned short*)(ws + off); off += (size_t)1024 * 256 * 2;
    unsigned short* w1h   = (unsigned short*)(ws + off); off += (size_t)1024 * 512 * 2;
    unsigned short* w1l   = (unsigned short*)(ws + off); off += (size_t)1024 * 512 * 2;
    unsigned short* sw1k8 = (unsigned short*)(ws + off); off += (size_t)256 * 128 * 2;
    float* Wih0T4 = (float*)(ws + off); off += (size_t)1024 * 512 * 4;
    float* x_const= (float*)(ws + off); off += (size_t)NB * 512 * 4;
    float* xw0    = (float*)(ws + off); off += (size_t)NB * 1024 * 4;
    float* b1sum  = (float*)(ws + off); off += (size_t)1024 * 4;
    float* hsum   = (float*)(ws + off); off += (size_t)NB * 256 * 4;
    float* basef  = (float*)(ws + off); off += (size_t)NB * TSTEPS * 4;
    off = (off + 255) & ~(size_t)255;
    unsigned* hbuf = (unsigned*)(ws + off); off += (size_t)131072 * 4;
    unsigned* flags= (unsigned*)(ws + off); off += (size_t)4096 * 4;

    init_sync<<<512, 256, 0, stream>>>(hbuf, flags);
    pack_bfrag_sliced<<<1024, 256, 0, stream>>>(Whh0, nullptr, 256, 0, whh0h, whh0l);
    pack_bfrag_sliced<<<2048, 256, 0, stream>>>(Wih1, Whh1, 256, 256, w1h, w1l);
    pack_sw1k8<<<128, 256, 0, stream>>>(sW1, sw1k8);
    pack4T<<<2048, 256, 0, stream>>>(Wih0, 1024, 512, Wih0T4);
    prep_b1<<<4, 256, 0, stream>>>(bih1, bhh1, b1sum);

    np_head<<<NB, 256, 0, stream>>>(z, labels, emb_W, np_W, np_b, np_g, np_be, x_const);
    xw0_kernel<<<NB, 1024, 0, stream>>>(x_const, (const float4*)Wih0T4, bih0, bhh0, xw0);
    lstm_coop<<<64, 512, 110848, stream>>>((const uint4*)whh0h, (const uint4*)whh0l,
                                           (const uint4*)w1h, (const uint4*)w1l,
                                           sw1k8, xw0, b1sum, sb1, sg, sbe, sW2, sb2,
                                           hbuf, flags, basef, hsum);
    out_kernel<<<NB, 256, 0, stream>>>(hsum, oW1, ob1, og, obe, oW2, ob2, basef, labels,
                                       stressw, amu_w, amu_b, out);
}